// Round 6
// baseline (306.561 us; speedup 1.0000x reference)
//
#include <hip/hip_runtime.h>
#include <hip/hip_bf16.h>

// MessagePassing: out[t] += x[s] for each edge (t, s), D=64.
// edge_index: [2, E] int32 (row 0 = targets, row 1 = sources), x: [N, 64] f32.
//
// Round-6 restructure: coarse bucket sort (512 buckets x ~98 nodes) with full
// LDS staging (coalesced pair writes; round-5's scatter wrote 52MB = 64B/line
// per random 4B store), then per-bucket fused accumulation in LDS f32 atomics
// (wave = one edge: 64 lanes = 64 dims, 2-way LDS banking = free) and one
// coalesced output write per node. No exact CSR, no ssrc, no out memset.

#define D 64
#define NB2 512        // coarse buckets
#define GPB_MAX 128    // max nodes/bucket supported by bsum LDS (N <= 65536)
#define EPB 4096       // edges per block in bhist/part
#define THR 256

// ---- A: bucket histogram (LDS-staged) ----
__global__ __launch_bounds__(THR) void bhist_kernel(const int* __restrict__ tgt,
                                                    int* __restrict__ bcnt,
                                                    int E, int gpb) {
    __shared__ int h[NB2];
    int t = threadIdx.x;
    for (int i = t; i < NB2; i += THR) h[i] = 0;
    __syncthreads();
    int base = blockIdx.x * EPB;
    #pragma unroll
    for (int k = 0; k < EPB / THR; ++k) {
        int e = base + t + k * THR;
        if (e < E) atomicAdd(&h[(unsigned)tgt[e] / (unsigned)gpb], 1);
    }
    __syncthreads();
    for (int i = t; i < NB2; i += THR) {
        int v = h[i];
        if (v) atomicAdd(&bcnt[i], v);
    }
}

// ---- B: exclusive scan of bcnt[NB2] -> boff[NB2+1], brun = boff ----
__global__ __launch_bounds__(THR) void bscan_kernel(const int* __restrict__ bcnt,
                                                    int* __restrict__ boff,
                                                    int* __restrict__ brun, int E) {
    __shared__ int a[THR];
    int t = threadIdx.x;
    int s0 = bcnt[2 * t], s1 = bcnt[2 * t + 1];
    a[t] = s0 + s1;
    __syncthreads();
    for (int d = 1; d < THR; d <<= 1) {
        int v = (t >= d) ? a[t - d] : 0;
        __syncthreads();
        a[t] += v;
        __syncthreads();
    }
    int ex = t ? a[t - 1] : 0;
    boff[2 * t] = ex;          brun[2 * t] = ex;
    boff[2 * t + 1] = ex + s0; brun[2 * t + 1] = ex + s0;
    if (t == THR - 1) boff[NB2] = E;
}

// ---- C: partition edges into bucket-grouped pairs (LDS-staged flush) ----
// pair word = (local_tgt << 16) | src   (requires N <= 65536)
__global__ __launch_bounds__(THR) void part_kernel(const int* __restrict__ tgt,
                                                   const int* __restrict__ src,
                                                   int* __restrict__ brun,
                                                   unsigned* __restrict__ pairs,
                                                   int E, int gpb) {
    __shared__ int h[NB2];
    __shared__ int coff[NB2];
    __shared__ int crun[NB2];
    __shared__ int gbase[NB2];
    __shared__ unsigned sw[EPB];
    __shared__ unsigned short sb[EPB];
    __shared__ int a[THR];
    int t = threadIdx.x;
    int base = blockIdx.x * EPB;
    for (int i = t; i < NB2; i += THR) h[i] = 0;
    __syncthreads();

    int myb[EPB / THR];
    unsigned myw[EPB / THR];
    #pragma unroll
    for (int k = 0; k < EPB / THR; ++k) {
        int e = base + t + k * THR;
        int bk = -1; unsigned w = 0;
        if (e < E) {
            unsigned tg = (unsigned)tgt[e];
            unsigned s  = (unsigned)src[e];
            bk = (int)(tg / (unsigned)gpb);
            unsigned lt = tg - (unsigned)bk * (unsigned)gpb;
            w = (lt << 16) | s;
            atomicAdd(&h[bk], 1);
        }
        myb[k] = bk; myw[k] = w;
    }
    __syncthreads();

    // exclusive scan of h (2 elems/thread)
    int s0 = h[2 * t], s1 = h[2 * t + 1];
    a[t] = s0 + s1;
    __syncthreads();
    for (int d = 1; d < THR; d <<= 1) {
        int v = (t >= d) ? a[t - d] : 0;
        __syncthreads();
        a[t] += v;
        __syncthreads();
    }
    int ex = t ? a[t - 1] : 0;
    coff[2 * t] = ex;          crun[2 * t] = ex;
    coff[2 * t + 1] = ex + s0; crun[2 * t + 1] = ex + s0;
    __syncthreads();

    // place into staging (bucket-grouped within block)
    #pragma unroll
    for (int k = 0; k < EPB / THR; ++k) {
        if (myb[k] >= 0) {
            int pos = atomicAdd(&crun[myb[k]], 1);
            sw[pos] = myw[k];
            sb[pos] = (unsigned short)myb[k];
        }
    }
    // reserve global space per bucket (h is stable)
    int b0 = t, b1 = t + THR;
    gbase[b0] = h[b0] ? atomicAdd(&brun[b0], h[b0]) : 0;
    gbase[b1] = h[b1] ? atomicAdd(&brun[b1], h[b1]) : 0;
    __syncthreads();

    // flush: consecutive i within a bucket run -> consecutive global dst
    int nitems = a[THR - 1];
    for (int i = t; i < nitems; i += THR) {
        int bk = sb[i];
        pairs[gbase[bk] + (i - coff[bk])] = sw[i];
    }
}

// ---- D: per-bucket accumulate in LDS + coalesced output ----
// One wave = one edge at a time (64 lanes = 64 dims), 8 edges in flight.
__global__ __launch_bounds__(THR) void bsum_kernel(const int* __restrict__ boff,
                                                   const unsigned* __restrict__ pairs,
                                                   const float* __restrict__ x,
                                                   float* __restrict__ out,
                                                   int N, int gpb) {
    __shared__ float acc[GPB_MAX * D];
    int b = blockIdx.x;
    int t = threadIdx.x;
    int lo = b * gpb;
    if (lo >= N) return;
    int hi = lo + gpb; if (hi > N) hi = N;
    int nn = hi - lo;
    for (int i = t; i < nn * D; i += THR) acc[i] = 0.f;
    __syncthreads();

    int s = boff[b], e = boff[b + 1];
    int m = e - s;
    int wid = t >> 6;
    int lane = t & 63;
    const unsigned* __restrict__ p = pairs + s;
    for (int jb = wid * 8; jb < m; jb += 32) {
        unsigned w[8]; float v[8];
        #pragma unroll
        for (int k = 0; k < 8; ++k) {
            int j = jb + k;
            w[k] = p[(j < m) ? j : (m - 1)];
        }
        #pragma unroll
        for (int k = 0; k < 8; ++k) {
            unsigned sidx = w[k] & 0xffffu;
            v[k] = x[sidx * D + lane];
        }
        #pragma unroll
        for (int k = 0; k < 8; ++k) {
            if (jb + k < m) {                 // wave-uniform predicate
                unsigned lt = w[k] >> 16;
                atomicAdd(&acc[lt * D + lane], v[k]);
            }
        }
    }
    __syncthreads();

    const float4* a4 = (const float4*)acc;
    float4* o4 = (float4*)(out + (size_t)lo * D);
    int n4 = nn * (D / 4);
    for (int i = t; i < n4; i += THR) o4[i] = a4[i];
}

// Fallback: direct atomic scatter-add.
__global__ void mp_scatter_add_kernel(const int* __restrict__ tgt,
                                      const int* __restrict__ src,
                                      const float* __restrict__ x,
                                      float* __restrict__ out,
                                      int E) {
    long long tid = (long long)blockIdx.x * blockDim.x + threadIdx.x;
    int e = (int)(tid >> 6);
    int d = (int)(tid & 63);
    if (e >= E) return;
    atomicAdd(&out[(long long)tgt[e] * D + d], x[(long long)src[e] * D + d]);
}

extern "C" void kernel_launch(void* const* d_in, const int* in_sizes, int n_in,
                              void* d_out, int out_size, void* d_ws, size_t ws_size,
                              hipStream_t stream) {
    const int* edge_index = (const int*)d_in[0];   // [2, E]
    const float* x        = (const float*)d_in[1]; // [N, 64]
    float* out            = (float*)d_out;         // [N, 64]

    int E = in_sizes[0] / 2;
    int N = out_size / D;
    const int* tgt = edge_index;       // edge_index[0]
    const int* src = edge_index + E;   // edge_index[1]

    int gpb = (N + NB2 - 1) / NB2;     // nodes per bucket (98 for N=50000)

    // ws layout (16B-aligned int segments): bcnt[512] | boff[516] | brun[512] | pairs[E]
    size_t need = (size_t)(NB2 + (NB2 + 4) + NB2 + E) * sizeof(int);

    if (N > 65536 || gpb > GPB_MAX || ws_size < need) {
        hipMemsetAsync(d_out, 0, (size_t)out_size * sizeof(float), stream);
        long long total = (long long)E * D;
        long long grid = (total + THR - 1) / THR;
        mp_scatter_add_kernel<<<(dim3)(unsigned)grid, THR, 0, stream>>>(tgt, src, x, out, E);
        return;
    }

    int* bcnt = (int*)d_ws;
    int* boff = bcnt + NB2;
    int* brun = boff + (NB2 + 4);
    unsigned* pairs = (unsigned*)(brun + NB2);

    hipMemsetAsync(bcnt, 0, NB2 * sizeof(int), stream);

    int GE = (E + EPB - 1) / EPB;
    bhist_kernel<<<GE, THR, 0, stream>>>(tgt, bcnt, E, gpb);
    bscan_kernel<<<1, THR, 0, stream>>>(bcnt, boff, brun, E);
    part_kernel<<<GE, THR, 0, stream>>>(tgt, src, brun, pairs, E, gpb);
    bsum_kernel<<<NB2, THR, 0, stream>>>(boff, pairs, x, out, N, gpb);
}